// Round 11
// baseline (1116.769 us; speedup 1.0000x reference)
//
#include <hip/hip_runtime.h>
#include <math.h>

#define NXY    192
#define CELLS  (NXY*NXY)
#define NBATCH 4
#define NSTEPS 256
#define TCH    16                 // steps per chunk (= halo radius)
#define NCHUNK (NSTEPS/TCH)       // 16
#define TPB    512                // 8 waves -> 2 waves/SIMD
#define NW     8
#define RPL    5                  // rows per wave (40-row window / 8 waves)
#define OUTR   6                  // out rows per tile
#define NBLKS  256                // 32 row-tiles x 2 col-tiles x 4 batches
// in-tile 128 cols x 40 rows; out-tile 96 cols x 6 rows (window rows [17,23))

// workspace layout (float offsets)
#define K3_OFF (16*CELLS)
#define Q_OFF  (K3_OFF + CELLS)
#define I_OFF  (Q_OFF + CELLS)
#define C_OFF  (I_OFF + 16)       // 20 sync counters, stride 32 ints

typedef float v2f __attribute__((ext_vector_type(2)));

__device__ __forceinline__ float dpp_up1(float v) {   // lane i <- lane i-1
    int r = __builtin_amdgcn_update_dpp(0, __builtin_bit_cast(int, v),
                                        0x138, 0xf, 0xf, true); // wave_shr:1
    return __builtin_bit_cast(float, r);
}
__device__ __forceinline__ float dpp_dn1(float v) {   // lane i <- lane i+1
    int r = __builtin_amdgcn_update_dpp(0, __builtin_bit_cast(int, v),
                                        0x130, 0xf, 0xf, true); // wave_shl:1
    return __builtin_bit_cast(float, r);
}

__device__ __forceinline__ float pml_prof(int i) {
    int t;
    if (i <= 20)            t = 20 - i;
    else if (i >= NXY - 21) t = i - (NXY - 21);
    else                    return 0.0f;
    float u  = (float)t * 0.05f;
    float u2 = u * u;
    return 3.0f * u2 * u2;
}

__global__ void init_k(float* __restrict__ ws) {
    int t = threadIdx.x;
    int* cnt = (int*)(ws + C_OFF);
    if (t < 20 * 32) cnt[t] = 0;
    if (t < 16) ws[I_OFF + t] = 0.0f;
}

// device-scope grid barrier; fresh counter per id (no reset race)
__device__ __forceinline__ void gsync(int* cnt, int id) {
    __syncthreads();
    if (threadIdx.x == 0) {
        __threadfence();   // release our global writes
        __hip_atomic_fetch_add(&cnt[id * 32], 1, __ATOMIC_ACQ_REL,
                               __HIP_MEMORY_SCOPE_AGENT);
        while (__hip_atomic_load(&cnt[id * 32], __ATOMIC_ACQUIRE,
                                 __HIP_MEMORY_SCOPE_AGENT) < NBLKS)
            __builtin_amdgcn_s_sleep(1);
    }
    __syncthreads();
    __threadfence();       // acquire
}

__global__ __launch_bounds__(TPB, 1)
void wave_k(const float* __restrict__ x, const float* __restrict__ rho,
            float* __restrict__ ws, float* __restrict__ out) {
    int* cnt = (int*)(ws + C_OFF);
    int blk = blockIdx.x;
    int t   = threadIdx.x;

    // ---- setup: zero parity-0 state + compute coefficients (grid-stride) ----
    {
        int gid = blk * TPB + t, gstride = NBLKS * TPB;
        for (int k = gid; k < 8 * CELLS; k += gstride) ws[k] = 0.0f;
        const float IH2 = (float)(1.0 / (2.01 * 2.01));
        for (int k = gid; k < CELLS; k += gstride) {
            int i = k / NXY, j = k % NXY;
            float r0 = rho[k];
            float ru = (i > 0)       ? rho[k - NXY] : 0.0f;
            float rd = (i < NXY - 1) ? rho[k + NXY] : 0.0f;
            float rl = (j > 0)       ? rho[k - 1]   : 0.0f;
            float rr2 = (j < NXY - 1) ? rho[k + 1]  : 0.0f;
            float lpf = 0.5f * r0 + 0.125f * ((ru + rd) + (rl + rr2));
            float p   = 0.5f * (1.0f + tanhf(100.0f * (lpf - 0.5f)));
            float c   = 1.0f - 0.1f * p;
            float c2h = c * c * IH2;
            float bx = pml_prof(i), by = pml_prof(j);
            float bb = sqrtf(bx * bx + by * by);
            float a1 = 1.0f / (1.0f + 0.5f * bb);
            ws[K3_OFF + k] = a1 * c2h;         // K
            ws[Q_OFF  + k] = 1.0f - 2.0f * a1; // Q
        }
    }

    // ---- per-block geometry (identical to R10) ----
    int b  = blk / 64;
    int r_ = blk % 64;
    int bi = r_ >> 1, cj = r_ & 1;
    int I0 = OUTR * bi - 17;          // window row origin (40 rows)
    int J0 = 96 * cj - 16;            // window col origin (128 cols)
    int w  = t >> 6;                  // wave 0..7, rows [5w,5w+5)
    int l  = t & 63;                  // lane: local cols 2l,2l+1
    int row0 = I0 + RPL * w;
    int gj   = J0 + 2 * l;

    __shared__ v2f hb[2][2][NW + 2][64];
    for (int k = t; k < 2 * 2 * (NW + 2) * 64; k += TPB)
        ((v2f*)hb)[k] = (v2f){0.f, 0.f};     // slots 0,9 stay zero forever

    gsync(cnt, 0);   // coefficients + zeroed state visible everywhere

    // ---- persistent per-lane coefficients ----
    const float* kg = ws + K3_OFF;
    const float* qg = ws + Q_OFF;
    v2f Qa[RPL], Ka[RPL];
    bool cok = (gj >= 0 && gj < NXY);
#pragma unroll
    for (int r = 0; r < RPL; r++) {
        int gi = row0 + r;
        bool ok = cok && gi >= 0 && gi < NXY;
        v2f kv = {0.f,0.f}, qv = {0.f,0.f};
        if (ok) {
            int idx = gi * NXY + gj;
            kv = *(const v2f*)(kg + idx);
            qv = *(const v2f*)(qg + idx);
        }
        Ka[r] = kv; Qa[r] = qv;   // out-of-domain: K=Q=0 -> cell stays 0 ✓
    }

    // source (40,96)
    int sr = 40 - I0, sc = 96 - J0;
    bool wave_src = (sr >= RPL * w) && (sr < RPL * w + RPL);
    int src_rl = sr - RPL * w;
    float srcm = (2 * l == sc) ? 1.f : 0.f;

    // probes (160,{48,96,144}): bi==26, window row 21 (wave 4, r=1)
    int pcl = 2 * l + J0;
    bool wave_prb = (bi == 26) && (w == 4);
    const int prb_rl = 1;
    bool is_prb = (cj == 0) ? (pcl == 48) : (pcl == 96 || pcl == 144);
    float prbm = is_prb ? 1.f : 0.f;
    float pacc = 0.f;             // accumulates across ALL chunks in-register

    v2f yc[RPL], yp[RPL], uph, dnh;

#define ROWC(CUR, PRV, rr_, UP, DN, XSV, YN) do {                              \
    v2f cv = CUR[rr_];                                                         \
    float lf0 = dpp_up1(cv.y);                                                 \
    float rt1 = dpp_dn1(cv.x);                                                 \
    v2f h = (v2f){lf0, rt1} + __builtin_shufflevector(cv, cv, 1, 0);           \
    v2f S = ((UP) + (DN)) + h;                                                 \
    YN = cv + Qa[rr_] * (PRV[rr_] - cv) + Ka[rr_] * (S - 4.0f * cv);           \
    if (wave_src && (rr_) == src_rl) YN.x += srcm * (XSV);                     \
    if (wave_prb && (rr_) == prb_rl) { float q = prbm * YN.x; pacc += q * YN.x; } \
} while (0)

#define STEP(CUR, PRV, PH, SIDX) do {                                          \
    v2f t0, t4;                                                                \
    ROWC(CUR, PRV, 0, uph,    CUR[1], xv[SIDX], t0);                           \
    ROWC(CUR, PRV, 4, CUR[3], dnh,    xv[SIDX], t4);                           \
    hb[PH][0][w + 1][l] = t0;                                                  \
    hb[PH][1][w + 1][l] = t4;                                                  \
    PRV[0] = t0; PRV[4] = t4;                                                  \
    _Pragma("unroll")                                                          \
    for (int r = 1; r <= 3; r++) {                                             \
        v2f y;                                                                 \
        ROWC(CUR, PRV, r, CUR[r - 1], CUR[r + 1], xv[SIDX], y);                \
        PRV[r] = y;                                                            \
    }                                                                          \
    __syncthreads();                                                           \
    uph = hb[PH][1][w][l];                                                     \
    dnh = hb[PH][0][w + 2][l];                                                 \
} while (0)

#pragma unroll 1
    for (int chunk = 0; chunk < NCHUNK; chunk++) {
        int pin = chunk & 1, pout = pin ^ 1;
        const float* curg  = ws + ((pin  * 2 + 0) * NBATCH + b) * CELLS;
        const float* prvg  = ws + ((pin  * 2 + 1) * NBATCH + b) * CELLS;
        float*       ncurg = ws + ((pout * 2 + 0) * NBATCH + b) * CELLS;
        float*       nprvg = ws + ((pout * 2 + 1) * NBATCH + b) * CELLS;

        // source amplitudes for this chunk
        float xv[TCH];
        int xbase = b * NSTEPS + chunk * TCH;
#pragma unroll
        for (int i = 0; i < TCH; i++) xv[i] = x[xbase + i];

        // load window state
#pragma unroll
        for (int r = 0; r < RPL; r++) {
            int gi = row0 + r;
            bool ok = cok && gi >= 0 && gi < NXY;
            v2f cv = {0.f,0.f}, pv = {0.f,0.f};
            if (ok) {
                int idx = gi * NXY + gj;
                cv = *(const v2f*)(curg + idx);
                pv = *(const v2f*)(prvg + idx);
            }
            yc[r] = cv; yp[r] = pv;
        }

        // prologue halo exchange (parity 0)
        hb[0][0][w + 1][l] = yc[0];
        hb[0][1][w + 1][l] = yc[4];
        __syncthreads();
        uph = hb[0][1][w][l];
        dnh = hb[0][0][w + 2][l];

#pragma unroll
        for (int s2 = 0; s2 < TCH / 2; s2++) {
            STEP(yc, yp, 1, 2 * s2);        // new cur -> yp
            STEP(yp, yc, 0, 2 * s2 + 1);    // new cur -> yc
        }
        // yc = y(t_end), yp = y(t_end-1); clean on window rows [16,24)

        // store out-tile: rows [6bi,6bi+6), lanes 8..55
#pragma unroll
        for (int r = 0; r < RPL; r++) {
            int gi = row0 + r;
            if (gi >= OUTR * bi && gi < OUTR * bi + OUTR && l >= 8 && l < 56) {
                int idx = gi * NXY + gj;
                *(v2f*)(ncurg + idx) = yc[r];
                *(v2f*)(nprvg + idx) = yp[r];
            }
        }
        gsync(cnt, 1 + chunk);
    }
#undef STEP
#undef ROWC

    // probe owners publish I (unique writer per (b,pid); plain store)
    if (wave_prb && is_prb) ws[I_OFF + b * 3 + (pcl / 48 - 1)] = pacc;
    gsync(cnt, 1 + NCHUNK);

    if (blk == 0 && t < 12) {
        const float* I = ws + I_OFF;
        int bb2 = t / 3;
        float s = I[3 * bb2] + I[3 * bb2 + 1] + I[3 * bb2 + 2];
        out[t] = I[t] / s;
    }
}

extern "C" void kernel_launch(void* const* d_in, const int* in_sizes, int n_in,
                              void* d_out, int out_size, void* d_ws, size_t ws_size,
                              hipStream_t stream) {
    const float* x   = (const float*)d_in[0];   // (4,256) fp32
    const float* rho = (const float*)d_in[1];   // (192,192) fp32
    float* ws  = (float*)d_ws;
    float* out = (float*)d_out;

    init_k<<<1, 640, 0, stream>>>(ws);
    wave_k<<<NBLKS, TPB, 0, stream>>>(x, rho, ws, out);
}

// Round 12
// 222.110 us; speedup vs baseline: 5.0280x; 5.0280x over previous
//
#include <hip/hip_runtime.h>
#include <math.h>

#define NXY    192
#define CELLS  (NXY*NXY)
#define NBATCH 4
#define NSTEPS 256
#define TCH    16                 // steps per chunk (= halo radius)
#define NCHUNK (NSTEPS/TCH)       // 16
#define TPB    512                // 8 waves -> 2 waves/SIMD
#define NW     8
#define RPL    5                  // valid rows per wave
#define OUTR   6                  // out rows per tile
#define NBLKS  256                // 32 row-tiles x 2 col-tiles x 4 batches
// in-tile 128 cols x 40 rows; out-tile 96 cols x 6 rows (window rows [17,23))
// 2-step ghost cycle: reg rows 0..8; valid band = reg 2..6

// workspace layout (float offsets)
#define K3_OFF (16*CELLS)
#define Q_OFF  (K3_OFF + CELLS)
#define I_OFF  (Q_OFF + CELLS)

typedef float v2f __attribute__((ext_vector_type(2)));

__device__ __forceinline__ float dpp_up1(float v) {   // lane i <- lane i-1
    int r = __builtin_amdgcn_update_dpp(0, __builtin_bit_cast(int, v),
                                        0x138, 0xf, 0xf, true); // wave_shr:1
    return __builtin_bit_cast(float, r);
}
__device__ __forceinline__ float dpp_dn1(float v) {   // lane i <- lane i+1
    int r = __builtin_amdgcn_update_dpp(0, __builtin_bit_cast(int, v),
                                        0x130, 0xf, 0xf, true); // wave_shl:1
    return __builtin_bit_cast(float, r);
}

__device__ __forceinline__ float pml_prof(int i) {
    int t;
    if (i <= 20)            t = 20 - i;
    else if (i >= NXY - 21) t = i - (NXY - 21);
    else                    return 0.0f;
    float u  = (float)t * 0.05f;
    float u2 = u * u;
    return 3.0f * u2 * u2;
}

__global__ void setup_k(const float* __restrict__ rho, float* __restrict__ ws) {
    int idx    = blockIdx.x * blockDim.x + threadIdx.x;
    int stride = gridDim.x * blockDim.x;
    for (int k = idx; k < 8 * CELLS; k += stride) ws[k] = 0.0f;  // parity-0 state
    const float IH2 = (float)(1.0 / (2.01 * 2.01));
    for (int k = idx; k < CELLS; k += stride) {
        int i = k / NXY, j = k % NXY;
        float r0 = rho[k];
        float ru = (i > 0)       ? rho[k - NXY] : 0.0f;
        float rd = (i < NXY - 1) ? rho[k + NXY] : 0.0f;
        float rl = (j > 0)       ? rho[k - 1]   : 0.0f;
        float rr2 = (j < NXY - 1) ? rho[k + 1]  : 0.0f;
        float lpf = 0.5f * r0 + 0.125f * ((ru + rd) + (rl + rr2));
        float p   = 0.5f * (1.0f + tanhf(100.0f * (lpf - 0.5f)));
        float c   = 1.0f - 0.1f * p;
        float c2h = c * c * IH2;
        float bx = pml_prof(i), by = pml_prof(j);
        float bb = sqrtf(bx * bx + by * by);
        float a1 = 1.0f / (1.0f + 0.5f * bb);
        ws[K3_OFF + k] = a1 * c2h;         // K
        ws[Q_OFF  + k] = 1.0f - 2.0f * a1; // Q
    }
    if (idx < 12) ws[I_OFF + idx] = 0.0f;
}

__global__ __launch_bounds__(TPB, 1)
void chunk_k(const float* __restrict__ x, float* __restrict__ ws, int chunk) {
    int blk = blockIdx.x;
    int b  = blk / 64;                // batch
    int r_ = blk % 64;
    int bi = r_ >> 1, cj = r_ & 1;    // 32 row-tiles x 2 col-tiles
    int I0 = OUTR * bi - 17;          // window row origin (40 rows)
    int J0 = 96 * cj - 16;            // window col origin (128 cols)
    int t  = threadIdx.x;
    int w  = t >> 6;                  // wave 0..7, valid rows [5w,5w+5) of window
    int l  = t & 63;                  // lane: local cols 2l, 2l+1
    int row0 = I0 + RPL * w - 2;      // global row of register row 0
    int gj   = J0 + 2 * l;

    // ghost exchange buffers, parity double-buffered:
    // T: consumer w reads slot w (items: yc[5w-2], yc[5w-1], yp[5w-1]);
    //    producer u writes slot u+1 (= its yc[5], yc[6], yp[6]); slot 0 = zeros.
    // B: consumer w reads slot w+1 (yc[5w+5], yc[5w+6], yp[5w+5]);
    //    producer u writes slot u (= its yc[2], yc[3], yp[2]); slot 8 = zeros.
    __shared__ v2f T[2][NW + 1][3][64];
    __shared__ v2f B[2][NW + 1][3][64];
    for (int k = t; k < 2 * (NW + 1) * 3 * 64; k += TPB) {
        ((v2f*)T)[k] = (v2f){0.f, 0.f};
        ((v2f*)B)[k] = (v2f){0.f, 0.f};
    }

    // source amplitudes for this chunk -> registers
    float xv[TCH];
    int xbase = b * NSTEPS + chunk * TCH;
#pragma unroll
    for (int i = 0; i < TCH; i++) xv[i] = x[xbase + i];

    const float* kg = ws + K3_OFF;
    const float* qg = ws + Q_OFF;
    int pin = chunk & 1, pout = pin ^ 1;
    const float* curg  = ws + ((pin  * 2 + 0) * NBATCH + b) * CELLS;
    const float* prvg  = ws + ((pin  * 2 + 1) * NBATCH + b) * CELLS;
    float*       ncurg = ws + ((pout * 2 + 0) * NBATCH + b) * CELLS;
    float*       nprvg = ws + ((pout * 2 + 1) * NBATCH + b) * CELLS;

    bool cok = (gj >= 0 && gj < NXY);

    // state: reg rows 0..8; valid band 2..6 loaded from global
    v2f yc[9], yp[9], Ka[9], Qa[9];
#pragma unroll
    for (int r = 2; r <= 6; r++) {
        int gi = row0 + r;
        bool ok = cok && gi >= 0 && gi < NXY;
        v2f cv = {0.f,0.f}, pv = {0.f,0.f};
        if (ok) {
            int idx = gi * NXY + gj;
            cv = *(const v2f*)(curg + idx);
            pv = *(const v2f*)(prvg + idx);
        }
        yc[r] = cv; yp[r] = pv;
    }
    // coefficients for computed rows 1..7 (ghost-row computes included)
#pragma unroll
    for (int r = 1; r <= 7; r++) {
        int gi = row0 + r;
        bool ok = cok && gi >= 0 && gi < NXY;
        v2f kv = {0.f,0.f}, qv = {0.f,0.f};
        if (ok) {
            int idx = gi * NXY + gj;
            kv = *(const v2f*)(kg + idx);
            qv = *(const v2f*)(qg + idx);
        }
        Ka[r] = kv; Qa[r] = qv;   // out-of-domain: K=Q=0 -> stays 0 ✓
    }

    // source (40,96): reg row index (uniform rule across redundant copies)
    int src_r = 40 - row0;
    int sc = 96 - J0;
    float srcm = (2 * l == sc) ? 1.f : 0.f;

    // probes (160,{48,96,144}): bi==26, window row 21 -> wave 4 only, reg 3
    int pcl = 2 * l + J0;
    int prb_r = 160 - row0;           // == 3 only for wave 4 when bi==26
    bool wave_prb = (bi == 26) && (w == 4);
    bool is_prb = (cj == 0) ? (pcl == 48) : (pcl == 96 || pcl == 144);
    float prbm = is_prb ? 1.f : 0.f;
    float pacc = 0.f;

#define ROWC(CUR, PRV, rr_, XSV) do {                                         \
    v2f cv = CUR[rr_];                                                         \
    float lf0 = dpp_up1(cv.y);                                                 \
    float rt1 = dpp_dn1(cv.x);                                                 \
    v2f h = (v2f){lf0, rt1} + __builtin_shufflevector(cv, cv, 1, 0);           \
    v2f S = (CUR[rr_ - 1] + CUR[rr_ + 1]) + h;                                 \
    v2f yn = cv + Qa[rr_] * (PRV[rr_] - cv) + Ka[rr_] * (S - 4.0f * cv);       \
    if ((rr_) == src_r) yn.x += srcm * (XSV);                                  \
    if (wave_prb && (rr_) == prb_r) { float q = prbm * yn.x; pacc += q * yn.x; } \
    PRV[rr_] = yn;                                                             \
} while (0)

    __syncthreads();   // T/B zeros visible

#pragma unroll
    for (int c = 0; c < TCH / 2; c++) {
        int p = c & 1;
        // ---- exchange: one barrier per 2 steps ----
        T[p][w + 1][0][l] = yc[5];
        T[p][w + 1][1][l] = yc[6];
        T[p][w + 1][2][l] = yp[6];
        B[p][w][0][l]     = yc[2];
        B[p][w][1][l]     = yc[3];
        B[p][w][2][l]     = yp[2];
        __syncthreads();
        yc[0] = T[p][w][0][l];
        yc[1] = T[p][w][1][l];
        yp[1] = T[p][w][2][l];
        yc[7] = B[p][w + 1][0][l];
        yc[8] = B[p][w + 1][1][l];
        yp[7] = B[p][w + 1][2][l];

        // ---- stepA: rows 1..7, interior first (bury ds_read latency) ----
        ROWC(yc, yp, 3, xv[2 * c]);
        ROWC(yc, yp, 4, xv[2 * c]);
        ROWC(yc, yp, 5, xv[2 * c]);
        ROWC(yc, yp, 2, xv[2 * c]);
        ROWC(yc, yp, 6, xv[2 * c]);
        ROWC(yc, yp, 1, xv[2 * c]);
        ROWC(yc, yp, 7, xv[2 * c]);
        // ---- stepB: rows 2..6 (register-only) ----
        ROWC(yp, yc, 2, xv[2 * c + 1]);
        ROWC(yp, yc, 3, xv[2 * c + 1]);
        ROWC(yp, yc, 5, xv[2 * c + 1]);
        ROWC(yp, yc, 6, xv[2 * c + 1]);
        ROWC(yp, yc, 4, xv[2 * c + 1]);
    }
#undef ROWC
    // yc = y(t_end) valid reg 2..6; yp = y(t_end-1) valid reg 1..7

    // store out-tile: rows [6bi, 6bi+6), lanes 8..55
#pragma unroll
    for (int r = 2; r <= 6; r++) {
        int gi = row0 + r;
        if (gi >= OUTR * bi && gi < OUTR * bi + OUTR && l >= 8 && l < 56) {
            int idx = gi * NXY + gj;
            *(v2f*)(ncurg + idx) = yc[r];
            *(v2f*)(nprvg + idx) = yp[r];
        }
    }
    // unique writer per (b,pid)
    if (wave_prb && is_prb)
        ws[I_OFF + b * 3 + (pcl / 48 - 1)] += pacc;
}

__global__ void final_k(const float* __restrict__ ws, float* __restrict__ out) {
    int t = threadIdx.x;
    if (t < 12) {
        const float* I = ws + I_OFF;
        int b = t / 3;
        float s = I[3 * b] + I[3 * b + 1] + I[3 * b + 2];
        out[t] = I[t] / s;
    }
}

extern "C" void kernel_launch(void* const* d_in, const int* in_sizes, int n_in,
                              void* d_out, int out_size, void* d_ws, size_t ws_size,
                              hipStream_t stream) {
    const float* x   = (const float*)d_in[0];   // (4,256) fp32
    const float* rho = (const float*)d_in[1];   // (192,192) fp32
    float* ws  = (float*)d_ws;
    float* out = (float*)d_out;

    setup_k<<<256, 256, 0, stream>>>(rho, ws);
    for (int c = 0; c < NCHUNK; c++)
        chunk_k<<<NBLKS, TPB, 0, stream>>>(x, ws, c);
    final_k<<<1, 64, 0, stream>>>(ws, out);
}